// Round 1
// baseline (203.039 us; speedup 1.0000x reference)
//
#include <hip/hip_runtime.h>

// Problem constants (from reference setup_inputs):
// b=16, c=64, l=8, h=56, w=56  ->  cl = 512, n = 56*56 = 3136
#define BATCH 16
#define CL    512
#define NSP   3136
#define N4    (NSP / 4)          // 784 float4 per (b,c) row
#define CGROUPS 4                // channel groups per block in pass 1
#define CPG   (CL / CGROUPS)     // 128 channels per group

// ---------------------------------------------------------------------------
// Pass 1: per-(b,i) projections g[b,i] = sum_c x*g_w[c], and the per-batch
// scalar sum_t[b] = sum_{i,c} x*theta_w[c] (mean applied in pass 2).
// Block: 256 threads = 64 i-lanes (float4 each) x 4 channel-groups.
// Grid:  (BATCH, ceil(N4/64)) = (16, 13).
// ---------------------------------------------------------------------------
__global__ __launch_bounds__(256) void sa_pass1(
    const float* __restrict__ x,        // [BATCH, CL, NSP]
    const float* __restrict__ theta_w,  // [CL]
    const float* __restrict__ g_w,      // [CL]
    float* __restrict__ g_out,          // [BATCH, NSP] (ws)
    float* __restrict__ m_out)          // [BATCH]      (ws, pre-zeroed)
{
    const int b     = blockIdx.x;
    const int chunk = blockIdx.y;
    const int tid   = threadIdx.x;
    const int tx    = tid & 63;        // i-lane within wave
    const int ty    = tid >> 6;        // channel group (wave-uniform: 0..3)
    const int i4    = chunk * 64 + tx; // float4 index into spatial dim
    const bool valid = (i4 < N4);

    const float4* xb = (const float4*)(x + (size_t)b * CL * NSP);

    float4 gv = make_float4(0.f, 0.f, 0.f, 0.f);
    float4 tv = make_float4(0.f, 0.f, 0.f, 0.f);
    if (valid) {
        const int c0 = ty * CPG;
        #pragma unroll 4
        for (int c = c0; c < c0 + CPG; ++c) {
            float4 xv = xb[(size_t)c * N4 + i4];   // coalesced: 64 lanes x 16B
            float gw = g_w[c];                     // wave-uniform -> s_load
            float tw = theta_w[c];
            gv.x += xv.x * gw; gv.y += xv.y * gw;
            gv.z += xv.z * gw; gv.w += xv.w * gw;
            tv.x += xv.x * tw; tv.y += xv.y * tw;
            tv.z += xv.z * tw; tv.w += xv.w * tw;
        }
    }

    __shared__ float4 sg[CGROUPS][64];
    __shared__ float4 st[CGROUPS][64];
    sg[ty][tx] = gv;
    st[ty][tx] = tv;
    __syncthreads();

    if (ty == 0) {   // wave 0 finishes the cross-group reduction
        float4 G = sg[0][tx];
        float4 T = st[0][tx];
        #pragma unroll
        for (int k = 1; k < CGROUPS; ++k) {
            float4 a = sg[k][tx];
            float4 t2 = st[k][tx];
            G.x += a.x;  G.y += a.y;  G.z += a.z;  G.w += a.w;
            T.x += t2.x; T.y += t2.y; T.z += t2.z; T.w += t2.w;
        }
        if (valid)
            ((float4*)g_out)[(size_t)b * N4 + i4] = G;

        // block-partial of sum_i t[b,i]; invalid lanes contributed zeros
        float s = T.x + T.y + T.z + T.w;
        #pragma unroll
        for (int off = 32; off > 0; off >>= 1)
            s += __shfl_down(s, off, 64);
        if (tx == 0)
            atomicAdd(&m_out[b], s);
    }
}

// ---------------------------------------------------------------------------
// Pass 2: out[b,c,i] = x[b,c,i] + (m[b]/NSP) * g[b,i] * h_w[c] + h_b[c]
// One thread per float4, fully coalesced.
// ---------------------------------------------------------------------------
__global__ __launch_bounds__(256) void sa_pass2(
    const float* __restrict__ x,
    const float* __restrict__ g_arr,   // [BATCH, NSP]
    const float* __restrict__ m_arr,   // [BATCH] (sum, not mean)
    const float* __restrict__ h_w,     // [CL]
    const float* __restrict__ h_b,     // [CL]
    float* __restrict__ out)
{
    const int f = blockIdx.x * blockDim.x + threadIdx.x;  // float4 index
    const int total4 = BATCH * CL * N4;                   // 6,422,528
    if (f >= total4) return;

    const int i4 = f % N4;
    const int bc = f / N4;
    const int c  = bc & (CL - 1);   // CL = 512 = 2^9
    const int b  = bc >> 9;

    float4 xv = ((const float4*)x)[f];
    float4 gv = ((const float4*)g_arr)[(size_t)b * N4 + i4];
    float  m  = m_arr[b] * (1.0f / (float)NSP);
    float  hw = h_w[c];
    float  hb = h_b[c];

    float4 o;
    o.x = xv.x + m * gv.x * hw + hb;
    o.y = xv.y + m * gv.y * hw + hb;
    o.z = xv.z + m * gv.z * hw + hb;
    o.w = xv.w + m * gv.w * hw + hb;
    ((float4*)out)[f] = o;
}

extern "C" void kernel_launch(void* const* d_in, const int* in_sizes, int n_in,
                              void* d_out, int out_size, void* d_ws, size_t ws_size,
                              hipStream_t stream)
{
    const float* x       = (const float*)d_in[0];
    const float* theta_w = (const float*)d_in[1];
    const float* g_w     = (const float*)d_in[2];
    const float* h_w     = (const float*)d_in[3];
    const float* h_b     = (const float*)d_in[4];
    float* out = (float*)d_out;

    // Workspace layout: [0..64)   floats : m[BATCH] (only first 16 used)
    //                   [64.. )   floats : g[BATCH*NSP] = 50176 floats
    float* m_ws = (float*)d_ws;
    float* g_ws = (float*)((char*)d_ws + 256);

    // ws is poisoned 0xAA before every timed call — zero the atomic targets.
    hipMemsetAsync(m_ws, 0, BATCH * sizeof(float), stream);

    dim3 grid1(BATCH, (N4 + 63) / 64);   // (16, 13)
    sa_pass1<<<grid1, 256, 0, stream>>>(x, theta_w, g_w, g_ws, m_ws);

    const int total4 = BATCH * CL * N4;
    sa_pass2<<<(total4 + 255) / 256, 256, 0, stream>>>(x, g_ws, m_ws, h_w, h_b, out);
}

// Round 3
// 200.355 us; speedup vs baseline: 1.0134x; 1.0134x over previous
//
#include <hip/hip_runtime.h>

// Problem constants (from reference setup_inputs):
// b=16, c=64, l=8, h=56, w=56  ->  cl = 512, n = 56*56 = 3136
#define BATCH 16
#define CL    512
#define NSP   3136
#define N4    (NSP / 4)            // 784 float4 per (b,c) row
#define CHUNK 32                   // i4 positions per pass-1 block
#define NCHUNK ((N4 + CHUNK - 1) / CHUNK)   // 25
#define GROUPS 8                   // channel groups per pass-1 block
#define CPG   (CL / GROUPS)        // 64 channels per group

// Native vector type usable with __builtin_nontemporal_store
typedef float nfloat4 __attribute__((ext_vector_type(4)));

// ---------------------------------------------------------------------------
// Pass 1: g[b,i] = sum_c x[b,c,i]*g_w[c]  (final, no partials)
//         t_part[b,chunk] = sum_{i in chunk} sum_c x[b,c,i]*theta_w[c]
// Block: 256 threads = 32 i4-lanes x 8 channel-groups (covers all 512 ch).
// Grid:  (BATCH, NCHUNK) = (16, 25) = 400 blocks.
// ---------------------------------------------------------------------------
__global__ __launch_bounds__(256) void sa_pass1(
    const float* __restrict__ x,        // [BATCH, CL, NSP]
    const float* __restrict__ theta_w,  // [CL]
    const float* __restrict__ g_w,      // [CL]
    float* __restrict__ g_out,          // [BATCH, NSP]     (ws)
    float* __restrict__ t_part)         // [BATCH, NCHUNK]  (ws)
{
    const int b     = blockIdx.x;
    const int chunk = blockIdx.y;
    const int tid   = threadIdx.x;
    const int tx    = tid & 31;          // i4 lane within chunk
    const int gq    = tid >> 5;          // channel group 0..7
    const int i4    = chunk * CHUNK + tx;
    const bool valid = (i4 < N4);

    const float4* xb = (const float4*)x + (size_t)b * CL * N4;

    float4 gv = make_float4(0.f, 0.f, 0.f, 0.f);
    float4 tv = make_float4(0.f, 0.f, 0.f, 0.f);
    if (valid) {
        const int c0 = gq * CPG;
        #pragma unroll 4
        for (int c = c0; c < c0 + CPG; ++c) {
            float4 xv = xb[(size_t)c * N4 + i4];   // 32 lanes x 16B contiguous
            float gw = g_w[c];
            float tw = theta_w[c];
            gv.x += xv.x * gw; gv.y += xv.y * gw;
            gv.z += xv.z * gw; gv.w += xv.w * gw;
            tv.x += xv.x * tw; tv.y += xv.y * tw;
            tv.z += xv.z * tw; tv.w += xv.w * tw;
        }
    }

    __shared__ float4 sg[GROUPS][CHUNK];
    __shared__ float4 st[GROUPS][CHUNK];
    sg[gq][tx] = gv;
    st[gq][tx] = tv;
    __syncthreads();

    if (tid < 32) {    // lanes 0..31 of wave 0 finish the reduction
        float4 G = sg[0][tx];
        float4 T = st[0][tx];
        #pragma unroll
        for (int k = 1; k < GROUPS; ++k) {
            float4 a  = sg[k][tx];
            float4 t2 = st[k][tx];
            G.x += a.x;  G.y += a.y;  G.z += a.z;  G.w += a.w;
            T.x += t2.x; T.y += t2.y; T.z += t2.z; T.w += t2.w;
        }
        if (valid)
            ((float4*)g_out)[(size_t)b * N4 + i4] = G;

        // chunk-partial of sum_i t; invalid lanes contributed zeros.
        float s = T.x + T.y + T.z + T.w;
        #pragma unroll
        for (int off = 16; off > 0; off >>= 1)
            s += __shfl_down(s, off, 32);    // width 32: stays in lanes 0..31
        if (tx == 0)
            t_part[b * NCHUNK + chunk] = s;
    }
}

// ---------------------------------------------------------------------------
// Pass 2: out[b,c,i] = x[b,c,i] + (m[b]/NSP)*g[b,i]*h_w[c] + h_b[c]
// Block covers 512 consecutive float4 (2 per thread); 401408 float4 per batch
// is divisible by 512, so each block sees exactly one batch.
// Grid: 6422528/512 = 12544 blocks.
// ---------------------------------------------------------------------------
#define P2_F4_PER_BLOCK 512
__global__ __launch_bounds__(256) void sa_pass2(
    const float* __restrict__ x,
    const float* __restrict__ g_arr,   // [BATCH, NSP]
    const float* __restrict__ t_part,  // [BATCH, NCHUNK]
    const float* __restrict__ h_w,     // [CL]
    const float* __restrict__ h_b,     // [CL]
    float* __restrict__ out)
{
    const int blk = blockIdx.x;
    const int b   = blk / ((CL * N4) / P2_F4_PER_BLOCK);   // blocks-per-batch = 784

    // Reduce the 25 t-partials for this batch -> m (once per block).
    __shared__ float sm;
    if (threadIdx.x < 32) {
        float v = (threadIdx.x < NCHUNK) ? t_part[b * NCHUNK + threadIdx.x] : 0.f;
        #pragma unroll
        for (int off = 16; off > 0; off >>= 1)
            v += __shfl_down(v, off, 32);
        if (threadIdx.x == 0)
            sm = v * (1.0f / (float)NSP);
    }
    __syncthreads();
    const float m = sm;

    const size_t base = (size_t)blk * P2_F4_PER_BLOCK + threadIdx.x;
    #pragma unroll
    for (int r = 0; r < P2_F4_PER_BLOCK / 256; ++r) {
        const size_t f = base + (size_t)r * 256;     // float4 index
        const int i4 = (int)(f % N4);
        const int bc = (int)(f / N4);
        const int c  = bc & (CL - 1);

        float4 xv = ((const float4*)x)[f];
        float4 gv = ((const float4*)g_arr)[(size_t)b * N4 + i4];
        const float hw = h_w[c];
        const float hb = h_b[c];
        const float mh = m * hw;

        nfloat4 o;
        o.x = xv.x + mh * gv.x + hb;
        o.y = xv.y + mh * gv.y + hb;
        o.z = xv.z + mh * gv.z + hb;
        o.w = xv.w + mh * gv.w + hb;
        // Nontemporal: out is never re-read; keep x resident in L2/L3.
        __builtin_nontemporal_store(o, (nfloat4*)out + f);
    }
}

extern "C" void kernel_launch(void* const* d_in, const int* in_sizes, int n_in,
                              void* d_out, int out_size, void* d_ws, size_t ws_size,
                              hipStream_t stream)
{
    const float* x       = (const float*)d_in[0];
    const float* theta_w = (const float*)d_in[1];
    const float* g_w     = (const float*)d_in[2];
    const float* h_w     = (const float*)d_in[3];
    const float* h_b     = (const float*)d_in[4];
    float* out = (float*)d_out;

    // Workspace layout (all fully written by pass1 before pass2 reads them;
    // no memset needed):
    //   [0, BATCH*NCHUNK floats)           : t_part
    //   [2048 B, 2048 B + BATCH*NSP floats): g
    float* t_ws = (float*)d_ws;
    float* g_ws = (float*)((char*)d_ws + 2048);

    dim3 grid1(BATCH, NCHUNK);   // (16, 25)
    sa_pass1<<<grid1, 256, 0, stream>>>(x, theta_w, g_w, g_ws, t_ws);

    const int total4 = BATCH * CL * N4;
    sa_pass2<<<total4 / P2_F4_PER_BLOCK, 256, 0, stream>>>(x, g_ws, t_ws, h_w, h_b, out);
}